// Round 13
// baseline (41.340 us; speedup 1.0000x reference)
//
#include <hip/hip_runtime.h>
#include <hip/hip_bf16.h>

// DIAGNOSTIC ROUND (x3 repeat): LBS skinning as bf16 MFMA GEMM (swapped
// operands). Structure = persistent-block shape: stage packed A once, then
// loop x3 over the SAME tile (w-load -> k-loop -> epilogue), idempotent
// stores, asm-opaqued pointers so iterations can't be CSE'd (rule #17).
// Purpose: lift skin above the 40-us harness fills so rocprof finally
// shows its counters; also probes natural per-block stagger (no barriers
// inside the loop). dur_us will be ~3x the real kernel; per-iter time and
// pipe utilizations are the readout.
// V=100000, N=96, K=208 (padded to 224 = 7 steps of 32)

typedef __attribute__((ext_vector_type(8))) short bf16x8;
typedef __attribute__((ext_vector_type(4))) float f32x4;

constexpr int J      = 52;
constexpr int NT     = 6;                  // 6 n-tiles of 16 -> N=96
constexpr int WAVES  = 4;
constexpr int MT     = 2;                  // m-tiles (16 verts) per wave
constexpr int VPW    = MT * 16;            // 32 verts per wave
constexpr int VPB    = WAVES * VPW;        // 128 verts per block
constexpr int KSTEPS = 7;
constexpr int REPEAT = 3;                  // diagnostic repeat factor

constexpr int SLOTS_FULL = 6 * NT * 64;    // 2304 slots, s = 0..5
constexpr int SLOTS_S6   = NT * 32;        // 192 slots, s = 6 (lgrp 0/1 only)
constexpr int ZSLOT      = SLOTS_FULL + SLOTS_S6;  // 2496: broadcast zero slot
constexpr int NSLOT      = ZSLOT + 1;      // 2497 slots written by pack_A
constexpr int S6_BASE_B  = SLOTS_FULL * 16;        // 36864
constexpr int Z_B        = ZSLOT * 16;             // 39936
constexpr int LDS_B      = 40960;          // staged A bytes
constexpr int SPAD       = 100;            // epilogue dwords per b
constexpr int SL_B       = 16 * SPAD * 4;  // 6400 B epilogue slice per wave

typedef const __attribute__((address_space(1))) char* gas1_t;
typedef __attribute__((address_space(3))) char* las3_t;

__device__ __forceinline__ unsigned pk2(float a, float b) {
    __hip_bfloat162 h = __float22bfloat162_rn(make_float2(a, b));
    return *reinterpret_cast<unsigned*>(&h);
}

__global__ __launch_bounds__(256) void pack_A(
    const float* __restrict__ xf,
    bf16x8* __restrict__ Bp)
{
    const int slot = blockIdx.x * 256 + threadIdx.x;
    if (slot >= NSLOT) return;

    if (slot == ZSLOT) {                       // broadcast zero slot
        union { bf16x8 v; unsigned w[4]; } z;
        z.w[0] = z.w[1] = z.w[2] = z.w[3] = 0u;
        Bp[slot] = z.v;
        return;
    }

    int s, t, l;
    if (slot < SLOTS_FULL) {
        s = slot / (NT * 64);
        const int rem = slot - s * (NT * 64);
        t = rem >> 6;
        l = rem & 63;
    } else {
        s = 6;
        const int rem = slot - SLOTS_FULL;
        t = rem >> 5;
        l = rem & 31;                          // lgrp 0/1 only
    }
    const int lgrp = l >> 4;
    const int lrow = l & 15;
    const int n = t * 16 + lrow;               // n = 3b + i, < 96
    const int b = n / 3;
    const int i = n - 3 * b;
    const int j0 = s * 8 + lgrp * 2;           // <= 50 for all stored slots

    const float4* __restrict__ xf4 = reinterpret_cast<const float4*>(xf);
    const float4 m0 = xf4[(b * J + j0) * 4 + i];
    const float4 m1 = xf4[(b * J + j0 + 1) * 4 + i];
    union { bf16x8 v; unsigned w[4]; } r;
    r.w[0] = pk2(m0.x, m0.y); r.w[1] = pk2(m0.z, m0.w);
    r.w[2] = pk2(m1.x, m1.y); r.w[3] = pk2(m1.z, m1.w);
    Bp[slot] = r.v;
}

__global__ __launch_bounds__(256, 2) void skin_x3diag(
    const float* __restrict__ verts,
    const float* __restrict__ weights,
    const bf16x8* __restrict__ Bp,
    float* __restrict__ out,
    int V)
{
    __shared__ __align__(16) char sBp[LDS_B];           // packed A (read-only)
    __shared__ __align__(16) char sSl[WAVES][SL_B];     // epilogue slices

    const int tid  = threadIdx.x;
    const int lane = tid & 63;
    const int wid  = tid >> 6;
    const int lgrp = lane >> 4;
    const int lrow = lane & 15;
    const int v0   = blockIdx.x * VPB;
    const int v0w  = v0 + wid * VPW;           // this wave's base vertex

    // ---- stage A once: 40 KB linear, wave-striped 1KB chunks ----
    {
        const char* g = (const char*)Bp;
        for (int p = wid; p < LDS_B / 1024; p += WAVES) {
            __builtin_amdgcn_global_load_lds(
                (gas1_t)(g + p * 1024 + lane * 16),
                (las3_t)(sBp + p * 1024), 16, 0, 0);
        }
    }
    __syncthreads();   // the only block barrier

    const float* wbase = weights;
    const float* vbase = verts;

    for (int it = 0; it < REPEAT; ++it) {
        // opaque the pointers: forces full reload/recompute per iteration
        asm volatile("" : "+s"(wbase), "+s"(vbase));

        // ---- per-tile reg loads (verts + weights) ----
        float hx[MT], hy[MT], hz[MT];
        float2 wv[MT][KSTEPS];
#pragma unroll
        for (int mt = 0; mt < MT; ++mt) {
            const int v   = v0w + mt * 16 + lrow;
            const int vcl = (v < V) ? v : (V - 1);   // clamped lanes never stored
            hx[mt] = vbase[3 * (size_t)vcl + 0];
            hy[mt] = vbase[3 * (size_t)vcl + 1];
            hz[mt] = vbase[3 * (size_t)vcl + 2];
            const float* wr = wbase + (size_t)vcl * J;
#pragma unroll
            for (int s = 0; s < KSTEPS; ++s) {
                const int j0 = s * 8 + lgrp * 2;
                wv[mt][s] = (j0 < J) ? *(const float2*)(wr + j0)
                                     : float2{0.f, 0.f};
            }
        }

        // ---- k-loop: pure LDS + VALU + MFMA ----
        f32x4 acc[MT][NT];
#pragma unroll
        for (int mt = 0; mt < MT; ++mt)
#pragma unroll
            for (int t = 0; t < NT; ++t)
                acc[mt][t] = f32x4{0.f, 0.f, 0.f, 0.f};

#pragma unroll
        for (int s = 0; s < KSTEPS; ++s) {
            bf16x8 frag[NT];
#pragma unroll
            for (int t = 0; t < NT; ++t) {
                if (s < 6) {
                    frag[t] = *(const bf16x8*)(sBp + ((s * NT + t) * 64 + lane) * 16);
                } else {
                    const char* p = (lane < 32)
                        ? (sBp + S6_BASE_B + (t * 32 + lane) * 16)
                        : (sBp + Z_B);             // 32-lane broadcast of zeros
                    frag[t] = *(const bf16x8*)p;
                }
            }
#pragma unroll
            for (int mt = 0; mt < MT; ++mt) {
                const float w0 = wv[mt][s].x, w1 = wv[mt][s].y;
                union { bf16x8 v; unsigned w[4]; } xf8;
                xf8.w[0] = pk2(w0 * hx[mt], w0 * hy[mt]);
                xf8.w[1] = pk2(w0 * hz[mt], w0);
                xf8.w[2] = pk2(w1 * hx[mt], w1 * hy[mt]);
                xf8.w[3] = pk2(w1 * hz[mt], w1);
#pragma unroll
                for (int t = 0; t < NT; ++t)
                    acc[mt][t] = __builtin_amdgcn_mfma_f32_16x16x32_bf16(
                        frag[t], xf8.v, acc[mt][t], 0, 0, 0);
            }
        }

        // ---- epilogue: wave-private padded slices, contiguous f4 stores ----
        char* const sl = sSl[wid];
        const long long validf = ((long long)V - v0w) * 3;
#pragma unroll
        for (int h = 0; h < 2; ++h) {
#pragma unroll
            for (int mt = 0; mt < MT; ++mt) {
                const int vloc = mt * 16 + lrow;
#pragma unroll
                for (int tt = 0; tt < 3; ++tt) {
                    const int t = 3 * h + tt;
#pragma unroll
                    for (int r = 0; r < 4; ++r) {
                        const int n  = 16 * t + lgrp * 4 + r;
                        const int b  = n / 3;
                        const int i  = n - 3 * b;
                        const int fl = (b - 16 * h) * SPAD + vloc * 3 + i;
                        *(float*)(sl + fl * 4) = acc[mt][t][r];
                    }
                }
            }
            // RAW fence (lgkm completes out of order)
            asm volatile("s_waitcnt lgkmcnt(0)" ::: "memory");
            __builtin_amdgcn_sched_barrier(0);

            f32x4 vals[6];
#pragma unroll
            for (int q = 0; q < 6; ++q) {
                const int f  = q * 64 + lane;
                const int bl = f / 24;
                const int rr = f - bl * 24;
                vals[q] = *(const f32x4*)(sl + bl * (SPAD * 4) + rr * 16);
            }
            // WAR fence (reads in regs before next half's writes)
            asm volatile("s_waitcnt lgkmcnt(0)" ::: "memory");
            __builtin_amdgcn_sched_barrier(0);

#pragma unroll
            for (int q = 0; q < 6; ++q) {
                const int f  = q * 64 + lane;
                const int bl = f / 24;
                const int rr = f - bl * 24;
                float* dst = out + (size_t)(16 * h + bl) * (size_t)V * 3
                                 + (size_t)v0w * 3 + rr * 4;
                if ((long long)(rr + 1) * 4 <= validf) {
                    *(float4*)dst = *(const float4*)&vals[q];
                } else if ((long long)rr * 4 < validf) {
#pragma unroll
                    for (int e = 0; e < 4; ++e)
                        if ((long long)(rr * 4 + e) < validf) dst[e] = vals[q][e];
                }
            }
        }
    }
}

extern "C" void kernel_launch(void* const* d_in, const int* in_sizes, int n_in,
                              void* d_out, int out_size, void* d_ws, size_t ws_size,
                              hipStream_t stream)
{
    const float* verts   = (const float*)d_in[0];
    const float* weights = (const float*)d_in[1];
    const float* xf      = (const float*)d_in[2];
    float* out = (float*)d_out;

    const int V = in_sizes[0] / 3;   // 100000
    bf16x8* Bp = (bf16x8*)d_ws;      // 39952 B written; 40960 B staged

    pack_A<<<(NSLOT + 255) / 256, 256, 0, stream>>>(xf, Bp);
    const int nblocks = (V + VPB - 1) / VPB;
    skin_x3diag<<<nblocks, 256, 0, stream>>>(verts, weights, Bp, out, V);
}

// Round 14
// 24.237 us; speedup vs baseline: 1.7056x; 1.7056x over previous
//
#include <hip/hip_runtime.h>
#include <hip/hip_bf16.h>

// LBS skinning as bf16 MFMA GEMM (swapped operands), SINGLE persistent
// kernel. Each of 512 blocks:
//   1) packs A[k=4j+c][n=3b+i]=M[b,j,i,c] into LDS fragment order from
//      FULLY-COALESCED xf float4 reads (26/thread; scatter happens on the
//      cheap one-time ds_write side, unlike R10's scattered-global fail),
//   2) grid-strides tiles of 128 verts: k-loop (7 MFMA steps) -> prefetch
//      next tile's weights -> padded-slice LDS-transpose epilogue with
//      contiguous float4 stores (R12 path, R10 fence discipline).
// Fixed costs amortized: no pack kernel, no d_ws, one launch; blocks
// desynchronize after tile 1 (R13 diag: steady-state pass ~ HBM floor).
// V=100000, N=96, K=208 (padded to 224 = 7 steps of 32)

typedef __attribute__((ext_vector_type(8))) short bf16x8;
typedef __attribute__((ext_vector_type(4))) float f32x4;

constexpr int J      = 52;
constexpr int NT     = 6;                  // 6 n-tiles of 16 -> N=96
constexpr int WAVES  = 4;
constexpr int MT     = 2;                  // m-tiles (16 verts) per wave
constexpr int VPW    = MT * 16;            // 32 verts per wave
constexpr int VPB    = WAVES * VPW;        // 128 verts per block
constexpr int KSTEPS = 7;
constexpr int GMAX   = 512;                // persistent grid (2 blocks/CU)

constexpr int BP_B   = KSTEPS * NT * 64 * 16;  // 43008 B full fragment layout
constexpr int SPAD   = 100;                // epilogue dwords per b (96 padded)
constexpr int SL_B   = 16 * SPAD * 4;      // 6400 B epilogue slice per wave
constexpr int NF4    = 32 * J * 4;         // 6656 float4 in xf (= 26*256)

__device__ __forceinline__ unsigned pk2(float a, float b) {
    __hip_bfloat162 h = __float22bfloat162_rn(make_float2(a, b));
    return *reinterpret_cast<unsigned*>(&h);
}

__global__ __launch_bounds__(256, 2) void skin_persist(
    const float* __restrict__ verts,
    const float* __restrict__ weights,
    const float* __restrict__ xf,
    float* __restrict__ out,
    int V, int ntiles, int gsize)
{
    __shared__ __align__(16) char sBp[BP_B];            // packed A (read-only)
    __shared__ __align__(16) char sSl[WAVES][SL_B];     // epilogue slices

    const int tid  = threadIdx.x;
    const int lane = tid & 63;
    const int wid  = tid >> 6;
    const int lgrp = lane >> 4;
    const int lrow = lane & 15;

    int tv = blockIdx.x;               // first tile (grid = min(GMAX, ntiles))

    // ---- issue tile-1 weight/vert loads (fly during the pack) ----
    float hx[MT], hy[MT], hz[MT];
    float2 wv[MT][KSTEPS];
#pragma unroll
    for (int mt = 0; mt < MT; ++mt) {
        const int v   = tv * VPB + wid * VPW + mt * 16 + lrow;
        const int vcl = (v < V) ? v : (V - 1);   // clamped lanes never stored
        hx[mt] = verts[3 * (size_t)vcl + 0];
        hy[mt] = verts[3 * (size_t)vcl + 1];
        hz[mt] = verts[3 * (size_t)vcl + 2];
        const float* wr = weights + (size_t)vcl * J;
#pragma unroll
        for (int s = 0; s < KSTEPS; ++s) {
            const int j0 = s * 8 + lgrp * 2;
            wv[mt][s] = (j0 < J) ? *(const float2*)(wr + j0) : float2{0.f, 0.f};
        }
    }

    // ---- in-block pack: coalesced xf stream -> LDS fragment layout ----
    // f4 index g = (b*J + j)*4 + i holds M[b,j,i,0..3]; row i=3 unused.
    {
        const float4* __restrict__ xf4 = reinterpret_cast<const float4*>(xf);
        for (int it = 0; it < NF4 / 256; ++it) {
            const int g = it * 256 + tid;
            const float4 m = xf4[g];           // fully coalesced
            const int b   = g / 208;           // 208 = J*4 f4 per batch
            const int rem = g - b * 208;
            const int j = rem >> 2;
            const int i = rem & 3;
            if (i < 3) {
                const int n    = 3 * b + i;    // < 96
                const int slot = ((j >> 3) * NT + (n >> 4)) * 64
                               + ((j >> 1) & 3) * 16 + (n & 15);
                uint2 d;
                d.x = pk2(m.x, m.y);
                d.y = pk2(m.z, m.w);
                *(uint2*)(sBp + slot * 16 + (j & 1) * 8) = d;   // j half: 8B
            }
        }
        // zero s=6, lgrp 2/3 slots (j0 >= 52 padding): 192 slots
        for (int z = tid; z < NT * 32; z += 256) {
            const int t = z >> 5, l = z & 31;
            const int slot = (6 * NT + t) * 64 + 32 + l;
            *(f32x4*)(sBp + slot * 16) = f32x4{0.f, 0.f, 0.f, 0.f};
        }
    }
    __syncthreads();   // the only block barrier; sBp read-only afterwards

    // ---- persistent tile loop ----
    for (;;) {
        // k-loop: pure LDS + VALU + MFMA (uniform frag reads, all s)
        f32x4 acc[MT][NT];
#pragma unroll
        for (int mt = 0; mt < MT; ++mt)
#pragma unroll
            for (int t = 0; t < NT; ++t)
                acc[mt][t] = f32x4{0.f, 0.f, 0.f, 0.f};

#pragma unroll
        for (int s = 0; s < KSTEPS; ++s) {
            bf16x8 frag[NT];
#pragma unroll
            for (int t = 0; t < NT; ++t)
                frag[t] = *(const bf16x8*)(sBp + ((s * NT + t) * 64 + lane) * 16);
#pragma unroll
            for (int mt = 0; mt < MT; ++mt) {
                const float w0 = wv[mt][s].x, w1 = wv[mt][s].y;
                union { bf16x8 v; unsigned w[4]; } xf8;
                xf8.w[0] = pk2(w0 * hx[mt], w0 * hy[mt]);
                xf8.w[1] = pk2(w0 * hz[mt], w0);
                xf8.w[2] = pk2(w1 * hx[mt], w1 * hy[mt]);
                xf8.w[3] = pk2(w1 * hz[mt], w1);
#pragma unroll
                for (int t = 0; t < NT; ++t)
                    acc[mt][t] = __builtin_amdgcn_mfma_f32_16x16x32_bf16(
                        frag[t], xf8.v, acc[mt][t], 0, 0, 0);
            }
        }

        // epilogue params for CURRENT tile (before wv/h are overwritten)
        const int v0w = tv * VPB + wid * VPW;
        const long long validf = ((long long)V - v0w) * 3;
        const int tvn = tv + gsize;

        // ---- prefetch NEXT tile's weights/verts (fly under the epilogue) ----
        if (tvn < ntiles) {
#pragma unroll
            for (int mt = 0; mt < MT; ++mt) {
                const int v   = tvn * VPB + wid * VPW + mt * 16 + lrow;
                const int vcl = (v < V) ? v : (V - 1);
                hx[mt] = verts[3 * (size_t)vcl + 0];
                hy[mt] = verts[3 * (size_t)vcl + 1];
                hz[mt] = verts[3 * (size_t)vcl + 2];
                const float* wr = weights + (size_t)vcl * J;
#pragma unroll
                for (int s = 0; s < KSTEPS; ++s) {
                    const int j0 = s * 8 + lgrp * 2;
                    wv[mt][s] = (j0 < J) ? *(const float2*)(wr + j0)
                                         : float2{0.f, 0.f};
                }
            }
        }

        // ---- epilogue: wave-private padded slices, contiguous f4 stores ----
        char* const sl = sSl[wid];
#pragma unroll
        for (int h = 0; h < 2; ++h) {
#pragma unroll
            for (int mt = 0; mt < MT; ++mt) {
                const int vloc = mt * 16 + lrow;
#pragma unroll
                for (int tt = 0; tt < 3; ++tt) {
                    const int t = 3 * h + tt;
#pragma unroll
                    for (int r = 0; r < 4; ++r) {
                        const int n  = 16 * t + lgrp * 4 + r;
                        const int b  = n / 3;
                        const int i  = n - 3 * b;
                        const int fl = (b - 16 * h) * SPAD + vloc * 3 + i;
                        *(float*)(sl + fl * 4) = acc[mt][t][r];
                    }
                }
            }
            // RAW fence: ds_writes complete before reads (lgkm out-of-order)
            asm volatile("s_waitcnt lgkmcnt(0)" ::: "memory");
            __builtin_amdgcn_sched_barrier(0);

            f32x4 vals[6];
#pragma unroll
            for (int q = 0; q < 6; ++q) {
                const int f  = q * 64 + lane;
                const int bl = f / 24;
                const int rr = f - bl * 24;
                vals[q] = *(const f32x4*)(sl + bl * (SPAD * 4) + rr * 16);
            }
            // WAR fence: reads in regs before next half's (or tile's) writes
            asm volatile("s_waitcnt lgkmcnt(0)" ::: "memory");
            __builtin_amdgcn_sched_barrier(0);

#pragma unroll
            for (int q = 0; q < 6; ++q) {
                const int f  = q * 64 + lane;
                const int bl = f / 24;
                const int rr = f - bl * 24;
                float* dst = out + (size_t)(16 * h + bl) * (size_t)V * 3
                                 + (size_t)v0w * 3 + rr * 4;
                if ((long long)(rr + 1) * 4 <= validf) {
                    *(float4*)dst = *(const float4*)&vals[q];
                } else if ((long long)rr * 4 < validf) {   // partial tail
#pragma unroll
                    for (int e = 0; e < 4; ++e)
                        if ((long long)(rr * 4 + e) < validf) dst[e] = vals[q][e];
                }
            }
        }

        if (tvn >= ntiles) break;
        tv = tvn;
    }
}

extern "C" void kernel_launch(void* const* d_in, const int* in_sizes, int n_in,
                              void* d_out, int out_size, void* d_ws, size_t ws_size,
                              hipStream_t stream)
{
    const float* verts   = (const float*)d_in[0];
    const float* weights = (const float*)d_in[1];
    const float* xf      = (const float*)d_in[2];
    float* out = (float*)d_out;

    const int V = in_sizes[0] / 3;               // 100000
    const int ntiles = (V + VPB - 1) / VPB;      // 782
    const int G = ntiles < GMAX ? ntiles : GMAX; // 512 persistent blocks

    skin_persist<<<G, 256, 0, stream>>>(verts, weights, xf, out, V, ntiles, G);
}